// Round 7
// baseline (8592.226 us; speedup 1.0000x reference)
//
#include <hip/hip_runtime.h>

// SinkhornAttention — literal-transcription correctness build (all fp32).
// T=S=4096, B=8, E=1024, BUCKET=16 -> nb=nkb=256. TAU=0.75, ITERS=8, SCALE=1/32.
// d_out = [ out (4096*8*1024) | attn_weights (8*256*256) | log_alpha (8*256*256) ] f32.
// Noise: JAX threefry2x32 partitionable: per element i, (x0,x1)=(hi,lo)=(0,i);
//   32-bit draw = bits1 ^ bits2 (XOR of BOTH output lanes — uses all 64 hash bits).
// Dead: legacy split-iota [r1/r2], (0,i)->x0 [r3/r4], (0,i)->x1 [r5], (i,0)->x0 [r6].

#define OUT_ELEMS 33554432
#define AW_ELEMS  524288

// ---------------- bucket mean (pool commutes with linear proj — exact) ------
// dst[(b*256+i)*1024+e] = mean_j src[((i*16+j)*8+b)*1024+e]
__global__ __launch_bounds__(256) void pool_k(const float* __restrict__ src,
                                              float* __restrict__ dst) {
  long idx = (long)blockIdx.x * 256 + threadIdx.x;   // 0..2097151
  int e = (int)(idx & 1023);
  int i = (int)((idx >> 10) & 255);
  int b = (int)(idx >> 18);
  const float* p = src + ((long)i * 128 + b) * 1024 + e;
  float s = 0.f;
  for (int j = 0; j < 16; ++j) s += p[(long)j * 8192];
  dst[idx] = s * 0.0625f;
}

// ---------------- generic 64x64-tile fp32 GEMM ------------------------------
// BT=true : C = A @ B^T ;  BT=false: C = A @ B
// C[cOff + z*cZ + m*cM + n] = scale * sum_k A[aOff+z*aZ+m*lda+k] * B[...] (+ bias[n])
template <bool BT>
__global__ __launch_bounds__(256) void g64(const float* __restrict__ A,
                                           const float* __restrict__ B,
                                           const float* __restrict__ bias,
                                           float* __restrict__ C,
                                           int K,
                                           long aOff, int lda, long aZ,
                                           long bOff, int ldb, long bZ,
                                           long cOff, int cM, long cZ,
                                           float scale) {
  __shared__ float As[64][65];
  __shared__ float Bs[64][65];
  const int z = blockIdx.z;
  const float* Ab = A + aOff + (long)z * aZ;
  const float* Bb = B + bOff + (long)z * bZ;
  const int m0 = blockIdx.x * 64, n0 = blockIdx.y * 64;
  const int tid = threadIdx.x, tx = tid & 15, ty = tid >> 4;
  float acc[4][4] = {};
  for (int k0 = 0; k0 < K; k0 += 64) {
    __syncthreads();
    #pragma unroll
    for (int i = 0; i < 16; ++i) {
      int l = tid + 256 * i;                 // 0..4095
      int r = l >> 6, c = l & 63;
      As[r][c] = Ab[(long)(m0 + r) * lda + k0 + c];
      if (BT) Bs[r][c] = Bb[(long)(n0 + r) * ldb + k0 + c];   // Bs[n][k]
      else    Bs[r][c] = Bb[(long)(k0 + r) * ldb + n0 + c];   // Bs[k][n]
    }
    __syncthreads();
    #pragma unroll 8
    for (int kk = 0; kk < 64; ++kk) {
      float a4[4], b4[4];
      #pragma unroll
      for (int i = 0; i < 4; ++i) a4[i] = As[ty * 4 + i][kk];
      #pragma unroll
      for (int i = 0; i < 4; ++i) b4[i] = BT ? Bs[tx * 4 + i][kk] : Bs[kk][tx * 4 + i];
      #pragma unroll
      for (int u = 0; u < 4; ++u)
        #pragma unroll
        for (int v = 0; v < 4; ++v) acc[u][v] += a4[u] * b4[v];
    }
  }
  #pragma unroll
  for (int u = 0; u < 4; ++u)
    #pragma unroll
    for (int v = 0; v < 4; ++v) {
      int m = m0 + ty * 4 + u, n = n0 + tx * 4 + v;
      float val = acc[u][v] * scale;
      if (bias) val += bias[n];
      C[cOff + (long)z * cZ + (long)m * cM + n] = val;
    }
}

// ---------------- JAX threefry2x32 gumbel ------------------------------------
__device__ __forceinline__ unsigned rotl32(unsigned x, int r) {
  return (x << r) | (x >> (32 - r));
}
__device__ __forceinline__ void threefry(unsigned c0, unsigned c1,
                                         unsigned* o0, unsigned* o1) {
  const unsigned k0 = 0u, k1 = 42u, k2 = 0u ^ 42u ^ 0x1BD11BDAu;
  unsigned x0 = c0 + k0, x1 = c1 + k1;
#define R4(a,b,c,d) \
  x0 += x1; x1 = rotl32(x1, a); x1 ^= x0; \
  x0 += x1; x1 = rotl32(x1, b); x1 ^= x0; \
  x0 += x1; x1 = rotl32(x1, c); x1 ^= x0; \
  x0 += x1; x1 = rotl32(x1, d); x1 ^= x0;
  R4(13,15,26,6)  x0 += k1; x1 += k2 + 1u;
  R4(17,29,16,24) x0 += k2; x1 += k0 + 2u;
  R4(13,15,26,6)  x0 += k0; x1 += k1 + 3u;
  R4(17,29,16,24) x0 += k1; x1 += k2 + 4u;
  R4(13,15,26,6)  x0 += k2; x1 += k0 + 5u;
#undef R4
  *o0 = x0; *o1 = x1;
}
__device__ __forceinline__ float bits_to_gumbel(unsigned bits) {
  float u = __builtin_bit_cast(float, (bits >> 9) | 0x3f800000u) - 1.0f;
  return -logf(-logf(u + 1e-6f) + 1e-6f);
}
__global__ __launch_bounds__(256) void gumbel_k(const float* __restrict__ logits,
                                                float* __restrict__ la) {
  unsigned i = blockIdx.x * 256 + threadIdx.x;       // 0..524287, grid 2048
  unsigned o0, o1;
  threefry(0u, i, &o0, &o1);                         // counts (hi,lo) = (0, i)
  la[i] = (logits[i] + bits_to_gumbel(o0 ^ o1)) / 0.75f;  // XOR both lanes
}

// ---------------- Sinkhorn, literal ------------------------------------------
__global__ __launch_bounds__(256) void srow_k(float* __restrict__ la) {
  int gid = blockIdx.x * 256 + threadIdx.x;
  int row = gid >> 6, lane = gid & 63;
  float* rp = la + (long)row * 256;
  float x0 = rp[lane], x1 = rp[lane + 64], x2 = rp[lane + 128], x3 = rp[lane + 192];
  float m = fmaxf(fmaxf(x0, x1), fmaxf(x2, x3));
  #pragma unroll
  for (int off = 32; off; off >>= 1) m = fmaxf(m, __shfl_xor(m, off, 64));
  float s = __expf(x0 - m) + __expf(x1 - m) + __expf(x2 - m) + __expf(x3 - m);
  #pragma unroll
  for (int off = 32; off; off >>= 1) s += __shfl_xor(s, off, 64);
  float lse = m + logf(s);
  rp[lane] = x0 - lse; rp[lane + 64] = x1 - lse;
  rp[lane + 128] = x2 - lse; rp[lane + 192] = x3 - lse;
}
__global__ __launch_bounds__(256) void scollse_k(const float* __restrict__ la,
                                                 float* __restrict__ cl) {
  int idx = blockIdx.x * 256 + threadIdx.x;          // 0..2047
  int k = idx & 255, b = idx >> 8;
  const float* p = la + (long)b * 65536 + k;
  float m = -3.0e38f, s = 0.f;
  for (int q = 0; q < 256; ++q) {
    float x = p[q * 256];
    if (x > m) { s = s * __expf(m - x) + 1.f; m = x; }
    else       { s += __expf(x - m); }
  }
  cl[idx] = m + logf(s);
}
__global__ __launch_bounds__(256) void scolsub_k(float* __restrict__ la,
                                                 const float* __restrict__ cl) {
  long idx = (long)blockIdx.x * 256 + threadIdx.x;   // 0..524287
  int k = (int)(idx & 255), b = (int)(idx >> 16);
  la[idx] -= cl[b * 256 + k];
}
__global__ __launch_bounds__(256) void sexp_k(const float* __restrict__ la,
                                              float* __restrict__ attnw) {
  long idx = (long)blockIdx.x * 256 + threadIdx.x;
  attnw[idx] = __expf(la[idx]);
}

// -----------------------------------------------------------------------------
extern "C" void kernel_launch(void* const* d_in, const int* in_sizes, int n_in,
                              void* d_out, int out_size, void* d_ws, size_t ws_size,
                              hipStream_t stream) {
  const float* query = (const float*)d_in[0];
  const float* key   = (const float*)d_in[1];
  const float* value = (const float*)d_in[2];
  const float* wq    = (const float*)d_in[3];
  const float* bq    = (const float*)d_in[4];
  const float* wk    = (const float*)d_in[5];
  const float* bk    = (const float*)d_in[6];
  const float* wo    = (const float*)d_in[7];
  const float* bo    = (const float*)d_in[8];

  float* out      = (float*)d_out;
  float* attnw    = out + OUT_ELEMS;
  float* logalpha = out + OUT_ELEMS + AW_ELEMS;

  const size_t MB = 1024 * 1024;
  if (ws_size < 52 * MB) return;
  char* ws = (char*)d_ws;
  float* qbar    = (float*)(ws + 0 * MB);        // 8 MB  (2048 x 1024)
  float* kbar    = (float*)(ws + 8 * MB);        // 8 MB
  float* qb2     = (float*)(ws + 16 * MB);       // 8 MB  projected pooled q
  float* kb2     = (float*)(ws + 24 * MB);       // 8 MB
  float* la      = (float*)(ws + 32 * MB);       // 2 MB
  float* cl      = (float*)(ws + 34 * MB);       // 8 KB
  float* attnbuf = (float*)(ws + 35 * MB);       // 16 MB (4096 x 1024, per-b)
  (void)in_sizes; (void)n_in; (void)out_size;

  pool_k<<<dim3(8192), 256, 0, stream>>>(query, qbar);
  pool_k<<<dim3(8192), 256, 0, stream>>>(key, kbar);

  // qb2[b][i][f] = sum_e qbar[b][i][e]*wq[f][e] + bq[f]
  g64<true><<<dim3(4, 16, 8), 256, 0, stream>>>(qbar, wq, bq, qb2, 1024,
      0, 1024, 262144,   0, 1024, 0,   0, 1024, 262144,  1.0f);
  g64<true><<<dim3(4, 16, 8), 256, 0, stream>>>(kbar, wk, bk, kb2, 1024,
      0, 1024, 262144,   0, 1024, 0,   0, 1024, 262144,  1.0f);

  // logalpha[b][q][k] = (qb2[b][q] . kb2[b][k]) / 32
  g64<true><<<dim3(4, 4, 8), 256, 0, stream>>>(qb2, kb2, nullptr, logalpha, 1024,
      0, 1024, 262144,   0, 1024, 262144,   0, 256, 65536,  0.03125f);

  gumbel_k<<<dim3(2048), 256, 0, stream>>>(logalpha, la);

  for (int it = 0; it < 8; ++it) {
    srow_k<<<dim3(512), 256, 0, stream>>>(la);
    scollse_k<<<dim3(8), 256, 0, stream>>>(la, cl);
    scolsub_k<<<dim3(2048), 256, 0, stream>>>(la, cl);
  }
  sexp_k<<<dim3(2048), 256, 0, stream>>>(la, attnw);

  for (int b = 0; b < 8; ++b) {
    // attnbuf[(q*16+j)][e] = sum_k attnw[b][q][k] * value[(k*16+j)][b][e]
    for (int j = 0; j < 16; ++j) {
      g64<false><<<dim3(4, 16, 1), 256, 0, stream>>>(attnw, value, nullptr, attnbuf, 256,
          (long)b * 65536, 256, 0,
          (long)j * 8192 + (long)b * 1024, 131072, 0,
          (long)j * 1024, 16384, 0,  1.0f);
    }
    // out[(t*8+b)*1024+f] = sum_e attnbuf[t][e]*wo[f][e] + bo[f]
    g64<true><<<dim3(64, 16, 1), 256, 0, stream>>>(attnbuf, wo, bo, out, 1024,
        0, 1024, 0,   0, 1024, 0,   (long)b * 1024, 8192, 0,  1.0f);
  }
}

// Round 8
// 457.901 us; speedup vs baseline: 18.7644x; 18.7644x over previous
//
#include <hip/hip_runtime.h>

// SinkhornAttention on MI355X — MFMA f16 build (round-1 pipeline + verified noise).
// Shapes: T=S=4096, B=8, E=1024, BUCKET=16 -> nb=nkb=256. TAU=0.75, ITERS=8, SCALE=1/32.
// d_out = [ out (4096*8*1024) | attn_weights (8*256*256) | log_alpha (8*256*256) ] f32.
// Noise (verified r7): threefry2x32 partitionable, counts (0,i), draw = o0 ^ o1.
// Bucket-mean commutes with the linear projection: pool first (16x less GEMM).

typedef float    f32x4 __attribute__((ext_vector_type(4)));
typedef _Float16 h4    __attribute__((ext_vector_type(4)));
typedef _Float16 h8    __attribute__((ext_vector_type(8)));

#define OUT_ELEMS 33554432
#define AW_ELEMS  524288

__device__ __forceinline__ void gload16(const void* g, void* l) {
  __builtin_amdgcn_global_load_lds((__attribute__((address_space(1))) void*)g,
                                   (__attribute__((address_space(3))) void*)l,
                                   16, 0, 0);
}

// ---------------- weight conversion f32 -> f16 -------------------------------
__global__ __launch_bounds__(256) void convw_k(const float* __restrict__ wq,
                                               const float* __restrict__ wk,
                                               const float* __restrict__ wo,
                                               _Float16* __restrict__ dst) {
  int which = blockIdx.y;
  const float* src = which == 0 ? wq : (which == 1 ? wk : wo);
  size_t idx = (size_t)blockIdx.x * 256 + threadIdx.x;            // float4 index
  f32x4 v = ((const f32x4*)src)[idx];
  ((h4*)(dst + (size_t)which * 1048576))[idx] = __builtin_convertvector(v, h4);
}

// ---------------- bucket mean over T (stride B*E), f32 -> f16 ----------------
// qbar[b*256+i][e] = mean_j query[(i*16+j)*8 + b][e]
__global__ __launch_bounds__(256) void bucket_k(const float* __restrict__ q,
                                                const float* __restrict__ k,
                                                _Float16* __restrict__ qbar,
                                                _Float16* __restrict__ kbar) {
  const float* src = blockIdx.y ? k : q;
  _Float16* dst = blockIdx.y ? kbar : qbar;
  unsigned t = blockIdx.x * 256 + threadIdx.x;                    // 0..524287
  int e4 = t & 255, i = (t >> 8) & 255, b = t >> 16;
  const f32x4* p = (const f32x4*)(src + ((size_t)(i * 16) * 8 + b) * 1024) + e4;
  f32x4 acc = {0.f, 0.f, 0.f, 0.f};
  #pragma unroll
  for (int j = 0; j < 16; ++j) acc += p[j * 2048];                // +8192 floats per row
  acc *= 0.0625f;
  ((h4*)(dst + (size_t)(b * 256 + i) * 1024))[e4] = __builtin_convertvector(acc, h4);
}

// ---------------- V transpose: vt[b][j][e][k] = v[(k*16+j)][b][e], f32->f16 --
__global__ __launch_bounds__(256) void vtrans_k(const float* __restrict__ v,
                                                _Float16* __restrict__ vt) {
  int bid = blockIdx.x;
  int kb = bid & 3, eb = (bid >> 2) & 15, j = (bid >> 6) & 15, b = bid >> 10;
  int k0 = kb * 64, e0 = eb * 64;
  __shared__ _Float16 tile[64][72];
  int t = threadIdx.x, r = t >> 2, qq = t & 3;
  const float* src = v + ((size_t)((k0 + r) * 16 + j) * 8 + b) * 1024 + e0;
  #pragma unroll
  for (int ii = 0; ii < 4; ++ii) {
    f32x4 x = ((const f32x4*)src)[qq + ii * 4];
    *(h4*)&tile[r][(qq + ii * 4) * 4] = __builtin_convertvector(x, h4);
  }
  __syncthreads();
  _Float16* dstp = vt + (((size_t)(b * 16 + j) * 1024 + e0 + r) * 256 + k0 + qq * 16);
  h8 o0, o1;
  #pragma unroll
  for (int kk = 0; kk < 8; ++kk) o0[kk] = tile[qq * 16 + kk][r];
  #pragma unroll
  for (int kk = 0; kk < 8; ++kk) o1[kk] = tile[qq * 16 + 8 + kk][r];
  *(h8*)dstp = o0;
  *(h8*)(dstp + 8) = o1;
}

// ---------------- JAX threefry2x32 gumbel (verified r7) ----------------------
__device__ __forceinline__ unsigned rotl32(unsigned x, int r) {
  return (x << r) | (x >> (32 - r));
}
__global__ __launch_bounds__(256) void gumbel_k(const float* __restrict__ logits,
                                                float* __restrict__ la,
                                                float* __restrict__ collse) {
  unsigned i = blockIdx.x * 256 + threadIdx.x;                    // 0..524287
  if (i < 2048) collse[i] = 0.f;                                  // init deferred col-LSE
  const unsigned k0 = 0u, k1 = 42u, k2 = 0u ^ 42u ^ 0x1BD11BDAu;
  unsigned x0 = 0u + k0, x1 = i + k1;                             // counts (hi,lo)=(0,i)
#define R4(a,b,c,d) \
  x0 += x1; x1 = rotl32(x1, a); x1 ^= x0; \
  x0 += x1; x1 = rotl32(x1, b); x1 ^= x0; \
  x0 += x1; x1 = rotl32(x1, c); x1 ^= x0; \
  x0 += x1; x1 = rotl32(x1, d); x1 ^= x0;
  R4(13,15,26,6)  x0 += k1; x1 += k2 + 1u;
  R4(17,29,16,24) x0 += k2; x1 += k0 + 2u;
  R4(13,15,26,6)  x0 += k0; x1 += k1 + 3u;
  R4(17,29,16,24) x0 += k1; x1 += k2 + 4u;
  R4(13,15,26,6)  x0 += k2; x1 += k0 + 5u;
#undef R4
  unsigned bits = x0 ^ x1;                                        // XOR both lanes
  float u = __builtin_bit_cast(float, (bits >> 9) | 0x3f800000u) - 1.0f;
  float g = -logf(-logf(u + 1e-6f) + 1e-6f);
  la[i] = (logits[i] + g) / 0.75f;
}

// ---------------- Sinkhorn row pass: la = (la - collse) - rowLSE -------------
__global__ __launch_bounds__(256) void sinkrow_k(float* __restrict__ la,
                                                 const float* __restrict__ collse) {
  int gid = blockIdx.x * 256 + threadIdx.x;
  int wid = gid >> 6;                                             // row = b*256+q
  int lane = gid & 63;
  int b = wid >> 8;
  f32x4 cl = ((const f32x4*)(collse + ((size_t)b << 8)))[lane];
  f32x4 x = ((const f32x4*)(la + ((size_t)wid << 8)))[lane];
  x -= cl;
  float m = fmaxf(fmaxf(x[0], x[1]), fmaxf(x[2], x[3]));
  #pragma unroll
  for (int off = 1; off < 64; off <<= 1) m = fmaxf(m, __shfl_xor(m, off, 64));
  float s = __expf(x[0]-m) + __expf(x[1]-m) + __expf(x[2]-m) + __expf(x[3]-m);
  #pragma unroll
  for (int off = 1; off < 64; off <<= 1) s += __shfl_xor(s, off, 64);
  float lse = m + logf(s);
  x -= lse;
  ((f32x4*)(la + ((size_t)wid << 8)))[lane] = x;
}

// ---------------- Sinkhorn col pass: collse[b][c] = LSE_q la[b][q][c] --------
__global__ __launch_bounds__(256) void sinkcol_k(const float* __restrict__ la,
                                                 float* __restrict__ collse) {
  int b = blockIdx.x >> 2, cg = blockIdx.x & 3;
  int cl = threadIdx.x & 63, q = threadIdx.x >> 6;
  int c = cg * 64 + cl;
  const float* base = la + (size_t)b * 65536;
  float m = -INFINITY, s = 0.f;
  #pragma unroll 4
  for (int i = 0; i < 64; ++i) {
    float x = base[(q * 64 + i) * 256 + c];
    float nm = fmaxf(m, x);
    s = s * __expf(m - nm) + __expf(x - nm);
    m = nm;
  }
  __shared__ float sm[4][64], ss[4][64];
  sm[q][cl] = m; ss[q][cl] = s;
  __syncthreads();
  if (q == 0) {
    float M = fmaxf(fmaxf(sm[0][cl], sm[1][cl]), fmaxf(sm[2][cl], sm[3][cl]));
    float S = ss[0][cl] * __expf(sm[0][cl] - M) + ss[1][cl] * __expf(sm[1][cl] - M)
            + ss[2][cl] * __expf(sm[2][cl] - M) + ss[3][cl] * __expf(sm[3][cl] - M);
    collse[(b << 8) + c] = M + logf(S);
  }
}

// ---------------- Sinkhorn final: w = exp(la - collse) -----------------------
__global__ __launch_bounds__(256) void sinkfinal_k(const float* __restrict__ la,
                                                   const float* __restrict__ collse,
                                                   float* __restrict__ attnw,
                                                   _Float16* __restrict__ wsh) {
  int idx = blockIdx.x * 256 + threadIdx.x;                       // 0..524287
  int c = idx & 255, b = idx >> 16;
  float w = __expf(la[idx] - collse[(b << 8) + c]);
  attnw[idx] = w;
  wsh[idx] = (_Float16)w;
}

// ---------------- generic 128x128 NT MFMA GEMM (m97 structure) ---------------
// C[M,N] = A[M,K] @ B[N,K]^T ; A,B f16 K-contiguous. 256 thr, 4 waves, BK=32.
// MODE 0: proj    -> f16 out (row*1024+col) + bias
// MODE 1: logits  -> f32 *1/32 to log_alpha[z*65536 + row*256 + col]
// MODE 2: attn    -> f16 attn[((z>>4)*4096 + row*16 + (z&15))*1024 + col]
// MODE 3: outproj -> f32 out[((row&4095)*8 + (row>>12))*1024 + col] + bias
template <int MODE>
__global__ __launch_bounds__(256) void gemm128(const _Float16* __restrict__ A,
                                               const _Float16* __restrict__ B,
                                               const float* __restrict__ bias,
                                               void* __restrict__ out0,
                                               int K, int lda, int ldb) {
  const int tid = threadIdx.x, lane = tid & 63, w = tid >> 6;
  const int m0 = blockIdx.x * 128, n0 = blockIdx.y * 128;
  const _Float16* Ab = A;
  const _Float16* Bb = B;
  if constexpr (MODE == 1) { Ab += (size_t)blockIdx.z * 262144; Bb += (size_t)blockIdx.z * 262144; }
  if constexpr (MODE == 2) { Ab += (size_t)(blockIdx.z >> 4) * 65536; Bb += (size_t)blockIdx.z * 262144; }
  __shared__ _Float16 lA[128 * 32];
  __shared__ _Float16 lB[128 * 32];
  f32x4 acc[4][4] = {};
  const int wm = (w >> 1) * 64, wn = (w & 1) * 64;
  const int fr = lane & 15, fk = (lane >> 4) * 8;
  const int q0 = tid, q1 = tid + 256;

  for (int kt = 0; kt < K; kt += 32) {
    __syncthreads();
    gload16(Ab + (size_t)(m0 + (q0 >> 2)) * lda + kt + (q0 & 3) * 8, &lA[(w * 64) * 8]);
    gload16(Ab + (size_t)(m0 + (q1 >> 2)) * lda + kt + (q1 & 3) * 8, &lA[(256 + w * 64) * 8]);
    gload16(Bb + (size_t)(n0 + (q0 >> 2)) * ldb + kt + (q0 & 3) * 8, &lB[(w * 64) * 8]);
    gload16(Bb + (size_t)(n0 + (q1 >> 2)) * ldb + kt + (q1 & 3) * 8, &lB[(256 + w * 64) * 8]);
    __syncthreads();
    h8 af[4], bf[4];
    #pragma unroll
    for (int i = 0; i < 4; ++i) {
      af[i] = *(const h8*)&lA[(wm + i * 16 + fr) * 32 + fk];
      bf[i] = *(const h8*)&lB[(wn + i * 16 + fr) * 32 + fk];
    }
    #pragma unroll
    for (int mi = 0; mi < 4; ++mi)
      #pragma unroll
      for (int ni = 0; ni < 4; ++ni)
        acc[mi][ni] = __builtin_amdgcn_mfma_f32_16x16x32_f16(af[mi], bf[ni], acc[mi][ni], 0, 0, 0);
  }

  const int er = (lane >> 4) * 4;
  #pragma unroll
  for (int mi = 0; mi < 4; ++mi) {
    #pragma unroll
    for (int ni = 0; ni < 4; ++ni) {
      #pragma unroll
      for (int r = 0; r < 4; ++r) {
        int row = m0 + wm + mi * 16 + er + r;
        int col = n0 + wn + ni * 16 + fr;
        float val = acc[mi][ni][r];
        if constexpr (MODE == 0) {
          ((_Float16*)out0)[(size_t)row * 1024 + col] = (_Float16)(val + bias[col]);
        } else if constexpr (MODE == 1) {
          ((float*)out0)[(size_t)blockIdx.z * 65536 + row * 256 + col] = val * 0.03125f;
        } else if constexpr (MODE == 2) {
          int b = blockIdx.z >> 4, j = blockIdx.z & 15;
          ((_Float16*)out0)[((size_t)(b * 4096 + row * 16 + j)) * 1024 + col] = (_Float16)val;
        } else {
          int bb = row >> 12, t = row & 4095;
          ((float*)out0)[((size_t)t * 8 + bb) * 1024 + col] = val + bias[col];
        }
      }
    }
  }
}

// -----------------------------------------------------------------------------
extern "C" void kernel_launch(void* const* d_in, const int* in_sizes, int n_in,
                              void* d_out, int out_size, void* d_ws, size_t ws_size,
                              hipStream_t stream) {
  const float* query = (const float*)d_in[0];
  const float* key   = (const float*)d_in[1];
  const float* value = (const float*)d_in[2];
  const float* wq    = (const float*)d_in[3];
  const float* bq    = (const float*)d_in[4];
  const float* wk    = (const float*)d_in[5];
  const float* bk    = (const float*)d_in[6];
  const float* wo    = (const float*)d_in[7];
  const float* bo    = (const float*)d_in[8];

  float* out      = (float*)d_out;
  float* attnw    = out + OUT_ELEMS;            // 8*256*256
  float* logalpha = out + OUT_ELEMS + AW_ELEMS; // logits (pre-noise)

  char* ws = (char*)d_ws;
  const size_t MB = 1024 * 1024;
  _Float16* wqh   = (_Float16*)(ws + 0 * MB);   // 2 MB
  _Float16* wkh   = (_Float16*)(ws + 2 * MB);   // 2 MB
  _Float16* woh   = (_Float16*)(ws + 4 * MB);   // 2 MB
  _Float16* qbar  = (_Float16*)(ws + 6 * MB);   // 4 MB  (2048x1024)
  _Float16* kbar  = (_Float16*)(ws + 10 * MB);  // 4 MB
  _Float16* qbh   = (_Float16*)(ws + 14 * MB);  // 4 MB  (projected, pooled q)
  _Float16* kbh   = (_Float16*)(ws + 18 * MB);  // 4 MB
  float*    la    = (float*)(ws + 22 * MB);     // 2 MB  sinkhorn state
  float*    colls = (float*)(ws + 24 * MB);     // 8 KB  deferred col-LSE
  _Float16* wsh   = (_Float16*)(ws + 25 * MB);  // 1 MB  attn weights f16
  _Float16* vt    = (_Float16*)(ws + 26 * MB);  // 64 MB vt[b][j][e][k]
  _Float16* attnh = (_Float16*)(ws + 90 * MB);  // 64 MB attn (B,T,E) f16
  (void)in_sizes; (void)n_in; (void)out_size; (void)ws_size;

  convw_k<<<dim3(1024, 3), 256, 0, stream>>>(wq, wk, wo, wqh);
  bucket_k<<<dim3(2048, 2), 256, 0, stream>>>(query, key, qbar, kbar);
  vtrans_k<<<dim3(8192), 256, 0, stream>>>(value, vt);

  gemm128<0><<<dim3(16, 8, 1), 256, 0, stream>>>(qbar, wqh, bq, qbh, 1024, 1024, 1024);
  gemm128<0><<<dim3(16, 8, 1), 256, 0, stream>>>(kbar, wkh, bk, kbh, 1024, 1024, 1024);
  gemm128<1><<<dim3(2, 2, 8), 256, 0, stream>>>(qbh, kbh, nullptr, logalpha, 1024, 1024, 1024);

  gumbel_k<<<dim3(2048), 256, 0, stream>>>(logalpha, la, colls);
  for (int it = 0; it < 8; ++it) {
    sinkrow_k<<<dim3(512), 256, 0, stream>>>(la, colls);
    sinkcol_k<<<dim3(32), 256, 0, stream>>>(la, colls);
  }
  sinkfinal_k<<<dim3(2048), 256, 0, stream>>>(la, colls, attnw, wsh);

  gemm128<2><<<dim3(2, 8, 128), 256, 0, stream>>>(wsh, vt, nullptr, attnh, 256, 256, 256);
  gemm128<3><<<dim3(256, 8, 1), 256, 0, stream>>>(attnh, woh, bo, out, 1024, 1024, 1024);
}